// Round 7
// baseline (633.694 us; speedup 1.0000x reference)
//
#include <hip/hip_runtime.h>
#include <hip/hip_fp16.h>
#include <math.h>

#define NN 50000
#define NE 800000
#define NN2 100000               // concatenated degD||degS
#define GEPS 1e-15f
#define BN_EPS 1e-5f
#define NB2 391                  // ceil((NN2+1)/256)

__device__ __forceinline__ float2 h2f(int bits) {
    __half2 h = *(__half2*)&bits;
    return __half22float2(h);
}
__device__ __forceinline__ int f2h2(float a, float b) {
    __half2 h = __floats2half2_rn(a, b);
    return *(int*)&h;
}

// dual histogram (deg2[0..NN)=dst, deg2[NN..2NN)=src) + (block 0) inv precompute
__global__ void hist_kernel(const int* __restrict__ ei, int* __restrict__ deg2,
                            const float* __restrict__ sig1, const float* __restrict__ sig2,
                            const float* __restrict__ sigs, float* __restrict__ inv) {
    if (blockIdx.x == 0) {
        int t = threadIdx.x;
        if (t < 15)      { float s = sig1[t];      inv[t] = -0.5f / (GEPS + s * s); }
        else if (t < 30) { float s = sig2[t - 15]; inv[t] = -0.5f / (GEPS + s * s); }
        else if (t < 33) { float s = sigs[t - 30]; inv[t] = -0.5f / (GEPS + s * s); }
    }
    int e = blockIdx.x * blockDim.x + threadIdx.x;
    if (e < NE) {
        atomicAdd(&deg2[ei[NE + e]], 1);       // dst
        atomicAdd(&deg2[NN + ei[e]], 1);       // src
    }
}

// ---- two-level scan over deg2[NN2] -> rs2[NN2+1], cursor2[NN2] ----
__global__ void block_reduce_kernel(const int* __restrict__ deg2, int* __restrict__ bsum) {
    __shared__ int sh[256];
    int t = threadIdx.x;
    int i = blockIdx.x * 256 + t;
    sh[t] = (i < NN2) ? deg2[i] : 0;
    __syncthreads();
    for (int off = 128; off > 0; off >>= 1) {
        if (t < off) sh[t] += sh[t + off];
        __syncthreads();
    }
    if (t == 0) bsum[blockIdx.x] = sh[0];
}

__global__ void scan_partials_kernel(int* __restrict__ bsum) {
    __shared__ int sh[512];
    int t = threadIdx.x;
    int v = (t < NB2) ? bsum[t] : 0;
    sh[t] = v;
    __syncthreads();
    for (int off = 1; off < 512; off <<= 1) {
        int u = (t >= off) ? sh[t - off] : 0;
        __syncthreads();
        sh[t] += u;
        __syncthreads();
    }
    if (t < NB2) bsum[t] = sh[t] - v;  // exclusive
}

__global__ void block_scan_kernel(const int* __restrict__ deg2, const int* __restrict__ bsum,
                                  int* __restrict__ rs2, int* __restrict__ cursor2) {
    __shared__ int sh[256];
    int t = threadIdx.x;
    int i = blockIdx.x * 256 + t;
    int v = (i < NN2) ? deg2[i] : 0;
    sh[t] = v;
    __syncthreads();
    for (int off = 1; off < 256; off <<= 1) {
        int u = (t >= off) ? sh[t - off] : 0;
        __syncthreads();
        sh[t] += u;
        __syncthreads();
    }
    int excl = sh[t] - v + bsum[blockIdx.x];
    if (i <= NN2) rs2[i] = excl;
    if (i < NN2) cursor2[i] = excl;
}

// ---- NEW path reorder: CSC-ordered weight recs carrying the CSR slot ----
// recsA[poss] = {posd, (w1_0,w1_1),(w1_2,w1_3),(w1_4,0)}
// recsB[poss] = {posd, (w2_0,w2_1),(w2_2,w2_3),(w2_4,0)}
// recsS[posd] = {src, (ws,0)}
__global__ void reorder_new_kernel(const int* __restrict__ ei, const float* __restrict__ ea,
                                   const float* __restrict__ mu1, const float* __restrict__ mu2,
                                   const float* __restrict__ mus, const float* __restrict__ inv,
                                   int* __restrict__ cursor2, int4* __restrict__ recsA,
                                   int4* __restrict__ recsB, int2* __restrict__ recsS) {
    int e = blockIdx.x * blockDim.x + threadIdx.x;
    if (e >= NE) return;
    int src = ei[e];
    int dst = ei[NE + e];
    float a0 = ea[e * 3 + 0], a1 = ea[e * 3 + 1], a2 = ea[e * 3 + 2];

    float w1[5], w2[5], ws;
#pragma unroll
    for (int k = 0; k < 5; k++) {
        float d0 = a0 - mu1[k * 3 + 0], d1 = a1 - mu1[k * 3 + 1], d2 = a2 - mu1[k * 3 + 2];
        w1[k] = __expf(inv[k * 3] * d0 * d0 + inv[k * 3 + 1] * d1 * d1 + inv[k * 3 + 2] * d2 * d2);
    }
#pragma unroll
    for (int k = 0; k < 5; k++) {
        float d0 = a0 - mu2[k * 3 + 0], d1 = a1 - mu2[k * 3 + 1], d2 = a2 - mu2[k * 3 + 2];
        w2[k] = __expf(inv[15 + k * 3] * d0 * d0 + inv[15 + k * 3 + 1] * d1 * d1 +
                       inv[15 + k * 3 + 2] * d2 * d2);
    }
    {
        float d0 = a0 - mus[0], d1 = a1 - mus[1], d2 = a2 - mus[2];
        ws = __expf(inv[30] * d0 * d0 + inv[31] * d1 * d1 + inv[32] * d2 * d2);
    }
    int posd = atomicAdd(&cursor2[dst], 1);
    int poss = atomicAdd(&cursor2[NN + src], 1) - NE;
    int4 ra, rb;
    ra.x = posd; ra.y = f2h2(w1[0], w1[1]); ra.z = f2h2(w1[2], w1[3]); ra.w = f2h2(w1[4], 0.f);
    rb.x = posd; rb.y = f2h2(w2[0], w2[1]); rb.z = f2h2(w2[2], w2[3]); rb.w = f2h2(w2[4], 0.f);
    recsA[poss] = ra;
    recsB[poss] = rb;
    int2 rs; rs.x = src; rs.y = f2h2(ws, 0.f);
    recsS[posd] = rs;
}

// ---- FALLBACK reorder (R6 format): CSR-ordered {src, weights} ----
__global__ void reorder_fb_kernel(const int* __restrict__ ei, const float* __restrict__ ea,
                                  const float* __restrict__ mu1, const float* __restrict__ mu2,
                                  const float* __restrict__ mus, const float* __restrict__ inv,
                                  int* __restrict__ cursor2, int4* __restrict__ recsA,
                                  int4* __restrict__ recsB) {
    int e = blockIdx.x * blockDim.x + threadIdx.x;
    if (e >= NE) return;
    int src = ei[e];
    int dst = ei[NE + e];
    float a0 = ea[e * 3 + 0], a1 = ea[e * 3 + 1], a2 = ea[e * 3 + 2];

    float w1[5], w2[5], ws;
#pragma unroll
    for (int k = 0; k < 5; k++) {
        float d0 = a0 - mu1[k * 3 + 0], d1 = a1 - mu1[k * 3 + 1], d2 = a2 - mu1[k * 3 + 2];
        w1[k] = __expf(inv[k * 3] * d0 * d0 + inv[k * 3 + 1] * d1 * d1 + inv[k * 3 + 2] * d2 * d2);
    }
#pragma unroll
    for (int k = 0; k < 5; k++) {
        float d0 = a0 - mu2[k * 3 + 0], d1 = a1 - mu2[k * 3 + 1], d2 = a2 - mu2[k * 3 + 2];
        w2[k] = __expf(inv[15 + k * 3] * d0 * d0 + inv[15 + k * 3 + 1] * d1 * d1 +
                       inv[15 + k * 3 + 2] * d2 * d2);
    }
    {
        float d0 = a0 - mus[0], d1 = a1 - mus[1], d2 = a2 - mus[2];
        ws = __expf(inv[30] * d0 * d0 + inv[31] * d1 * d1 + inv[32] * d2 * d2);
    }
    int pos = atomicAdd(&cursor2[dst], 1);
    int4 ra, rb;
    ra.x = src; ra.y = f2h2(w1[0], w1[1]); ra.z = f2h2(w1[2], w1[3]); ra.w = f2h2(w1[4], ws);
    rb.x = src; rb.y = f2h2(w2[0], w2[1]); rb.z = f2h2(w2[2], w2[3]); rb.w = f2h2(w2[4], 0.f);
    recsA[pos] = ra;
    recsB[pos] = rb;
}

// pass A projection: x -> PA[n][192] fp16 (0..159: g1-proj, 160..191: gs-proj),
//                    R1[n][32] fp32 (x@root1+b1), Rs[n][32] fp32 (x@roots+bs). block=256.
__global__ void projA_kernel(const float* __restrict__ x, const float* __restrict__ g1,
                             const float* __restrict__ gs, const float* __restrict__ root1,
                             const float* __restrict__ b1, const float* __restrict__ roots,
                             const float* __restrict__ bs, __half* __restrict__ PA,
                             float* __restrict__ R1, float* __restrict__ Rs) {
    const int t = threadIdx.x;
    float w[32];
    float b = 0.0f;
    if (t < 160) {
#pragma unroll
        for (int i = 0; i < 32; i++) w[i] = g1[i * 160 + t];
    } else if (t < 192) {
        int c = t - 160;
#pragma unroll
        for (int i = 0; i < 32; i++) w[i] = gs[i * 32 + c];
    } else if (t < 224) {
        int c = t - 192;
#pragma unroll
        for (int i = 0; i < 32; i++) w[i] = root1[i * 32 + c];
        b = b1[c];
    } else {
        int c = t - 224;
#pragma unroll
        for (int i = 0; i < 32; i++) w[i] = roots[i * 32 + c];
        b = bs[c];
    }
    __shared__ float xs[8 * 32];
    for (int n0 = blockIdx.x * 8; n0 < NN; n0 += gridDim.x * 8) {
        int rows = NN - n0; if (rows > 8) rows = 8;
        for (int j = t; j < rows * 32; j += 256) xs[j] = x[(size_t)n0 * 32 + j];
        __syncthreads();
        for (int r = 0; r < rows; r++) {
            float acc = b;
#pragma unroll
            for (int i = 0; i < 32; i++) acc += w[i] * xs[r * 32 + i];
            int n = n0 + r;
            if (t < 192) PA[(size_t)n * 192 + t] = __float2half(acc);
            else if (t < 224) R1[(size_t)n * 32 + (t - 192)] = acc;
            else Rs[(size_t)n * 32 + (t - 224)] = acc;
        }
        __syncthreads();
    }
}

// ---- NEW: message kernel (CSC). One wave per src; row preloaded in registers;
// two edges per iteration (half-wave each); one coalesced 64B store per edge. ----
__global__ void msg_kernel(const int4* __restrict__ recs, const int* __restrict__ rs2,
                           const __half* __restrict__ T, int strideH, __half* __restrict__ M) {
    const int tid = blockIdx.x * blockDim.x + threadIdx.x;
    const int lane = threadIdx.x & 63;
    const int ch = lane & 31;
    const int half = lane >> 5;
    const int wavesTotal = (gridDim.x * blockDim.x) >> 6;
    const int wid = tid >> 6;
    for (int s = wid; s < NN; s += wavesTotal) {
        const int start = rs2[NN + s] - NE;
        const int end   = rs2[NN + s + 1] - NE;
        if (start >= end) continue;
        const __half* row = T + (size_t)s * strideH;
        float v0 = __half2float(row[ch]);
        float v1 = __half2float(row[32 + ch]);
        float v2 = __half2float(row[64 + ch]);
        float v3 = __half2float(row[96 + ch]);
        float v4 = __half2float(row[128 + ch]);
        for (int pos = start + half; pos < end; pos += 2) {
            int4 q = recs[pos];
            float2 u0 = h2f(q.y), u1 = h2f(q.z), u2 = h2f(q.w);
            float m = u0.x * v0 + u0.y * v1 + u1.x * v2 + u1.y * v3 + u2.x * v4;
            M[(size_t)q.x * 32 + ch] = __float2half(m);
        }
    }
}

// ---- NEW: aggA. Conv half streams M rows; skip half gathers 1 line/edge. ----
__global__ void aggA_kernel(const __half* __restrict__ M, const int2* __restrict__ recsS,
                            const int* __restrict__ rs2, const __half* __restrict__ PA,
                            const float* __restrict__ R, const float* __restrict__ Rs,
                            float* __restrict__ c, float* __restrict__ cs,
                            float* __restrict__ stats) {
    const int tid = blockIdx.x * blockDim.x + threadIdx.x;
    const int lane = threadIdx.x & 63;
    const int ch = lane & 31;
    const int half = lane >> 5;
    const int wavesTotal = (gridDim.x * blockDim.x) >> 6;
    const int wid = tid >> 6;

    __shared__ float sh[128];
    if (threadIdx.x < 128) sh[threadIdx.x] = 0.f;
    __syncthreads();

    for (int n = wid; n < NN; n += wavesTotal) {
        const int start = rs2[n];
        const int end = rs2[n + 1];
        float acc = 0.f;
        if (half == 0) {
            for (int pos = start; pos < end; pos++)
                acc += __half2float(M[(size_t)pos * 32 + ch]);
        } else {
            for (int pos = start; pos < end; pos++) {
                int2 sr = recsS[pos];
                acc += h2f(sr.y).x * __half2float(PA[(size_t)sr.x * 192 + 160 + ch]);
            }
        }
        const float invd = 1.0f / fmaxf((float)(end - start), 1.0f);
        if (half == 0) {
            float v = acc * invd + R[(size_t)n * 32 + ch];
            c[(size_t)n * 32 + ch] = v;
            atomicAdd(&sh[ch], v);
            atomicAdd(&sh[32 + ch], v * v);
        } else {
            float vs = acc * invd + Rs[(size_t)n * 32 + ch];
            cs[(size_t)n * 32 + ch] = vs;
            atomicAdd(&sh[64 + ch], vs);
            atomicAdd(&sh[96 + ch], vs * vs);
        }
    }
    __syncthreads();
    if (threadIdx.x < 128) atomicAdd(&stats[threadIdx.x], sh[threadIdx.x]);
}

// ---- NEW: aggB. Pure streaming reduce of M rows (2 edges/iter). ----
__global__ void aggB_kernel(const __half* __restrict__ M, const int* __restrict__ rs2,
                            const float* __restrict__ R, float* __restrict__ c,
                            float* __restrict__ stats) {
    const int tid = blockIdx.x * blockDim.x + threadIdx.x;
    const int lane = threadIdx.x & 63;
    const int ch = lane & 31;
    const int half = lane >> 5;
    const int wavesTotal = (gridDim.x * blockDim.x) >> 6;
    const int wid = tid >> 6;

    __shared__ float sh[64];
    if (threadIdx.x < 64) sh[threadIdx.x] = 0.f;
    __syncthreads();

    for (int n = wid; n < NN; n += wavesTotal) {
        const int start = rs2[n];
        const int end = rs2[n + 1];
        float acc = 0.f;
        for (int pos = start + half; pos < end; pos += 2)
            acc += __half2float(M[(size_t)pos * 32 + ch]);
        acc += __shfl_xor(acc, 32, 64);
        const float invd = 1.0f / fmaxf((float)(end - start), 1.0f);
        if (half == 0) {
            float v = acc * invd + R[(size_t)n * 32 + ch];
            c[(size_t)n * 32 + ch] = v;
            atomicAdd(&sh[ch], v);
            atomicAdd(&sh[32 + ch], v * v);
        }
    }
    __syncthreads();
    if (threadIdx.x < 64) atomicAdd(&stats[threadIdx.x], sh[threadIdx.x]);
}

// ---- FALLBACK agg (R6, proven): CSR gather, 16B recs ----
template <bool SKIP>
__global__ void agg_fb_kernel(const int4* __restrict__ recs, const int* __restrict__ rowstart,
                              const __half2* __restrict__ P, int strideH2,
                              const float* __restrict__ R, const float* __restrict__ Rs,
                              float* __restrict__ c, float* __restrict__ cs,
                              float* __restrict__ stats) {
    const int tid = blockIdx.x * blockDim.x + threadIdx.x;
    const int lane = threadIdx.x & 63;
    const int grp = lane >> 4;
    const int ch2 = lane & 15;
    const int wavesTotal = (gridDim.x * blockDim.x) >> 6;
    const int wid = tid >> 6;

    float s1x = 0.f, s1y = 0.f, q1x = 0.f, q1y = 0.f;
    float ssx = 0.f, ssy = 0.f, qsx = 0.f, qsy = 0.f;

    for (int n = wid; n < NN; n += wavesTotal) {
        const int start = rowstart[n];
        const int end = rowstart[n + 1];
        const int d = end - start;
        float m1x = 0.f, m1y = 0.f, mSx = 0.f, mSy = 0.f;
        for (int i = start + grp; i < end; i += 4) {
            const int4 q = recs[i];
            const __half2* prow = P + (size_t)q.x * strideH2 + ch2;
            float2 p0 = __half22float2(prow[0]);
            float2 p1 = __half22float2(prow[16]);
            float2 p2 = __half22float2(prow[32]);
            float2 p3 = __half22float2(prow[48]);
            float2 p4 = __half22float2(prow[64]);
            float2 u0 = h2f(q.y), u1 = h2f(q.z), u2 = h2f(q.w);
            m1x += u0.x * p0.x + u0.y * p1.x + u1.x * p2.x + u1.y * p3.x + u2.x * p4.x;
            m1y += u0.x * p0.y + u0.y * p1.y + u1.x * p2.y + u1.y * p3.y + u2.x * p4.y;
            if (SKIP) {
                float2 ps = __half22float2(prow[80]);
                mSx += u2.y * ps.x;
                mSy += u2.y * ps.y;
            }
        }
        m1x += __shfl_xor(m1x, 16, 64); m1x += __shfl_xor(m1x, 32, 64);
        m1y += __shfl_xor(m1y, 16, 64); m1y += __shfl_xor(m1y, 32, 64);
        if (SKIP) {
            mSx += __shfl_xor(mSx, 16, 64); mSx += __shfl_xor(mSx, 32, 64);
            mSy += __shfl_xor(mSy, 16, 64); mSy += __shfl_xor(mSy, 32, 64);
        }
        const float invd = 1.0f / fmaxf((float)d, 1.0f);
        if (grp == 0) {
            float2 rv = ((const float2*)(R + (size_t)n * 32))[ch2];
            float vx = m1x * invd + rv.x;
            float vy = m1y * invd + rv.y;
            ((float2*)(c + (size_t)n * 32))[ch2] = make_float2(vx, vy);
            s1x += vx; s1y += vy; q1x += vx * vx; q1y += vy * vy;
            if (SKIP) {
                float2 rs = ((const float2*)(Rs + (size_t)n * 32))[ch2];
                float wx = mSx * invd + rs.x;
                float wy = mSy * invd + rs.y;
                ((float2*)(cs + (size_t)n * 32))[ch2] = make_float2(wx, wy);
                ssx += wx; ssy += wy; qsx += wx * wx; qsy += wy * wy;
            }
        }
    }
    __shared__ float sh[128];
    const int t = threadIdx.x;
    if (t < 128) sh[t] = 0.f;
    __syncthreads();
    if (grp == 0) {
        atomicAdd(&sh[2 * ch2], s1x);       atomicAdd(&sh[2 * ch2 + 1], s1y);
        atomicAdd(&sh[32 + 2 * ch2], q1x);  atomicAdd(&sh[32 + 2 * ch2 + 1], q1y);
        if (SKIP) {
            atomicAdd(&sh[64 + 2 * ch2], ssx);  atomicAdd(&sh[64 + 2 * ch2 + 1], ssy);
            atomicAdd(&sh[96 + 2 * ch2], qsx);  atomicAdd(&sh[96 + 2 * ch2 + 1], qsy);
        }
    }
    __syncthreads();
    if (SKIP) { if (t < 128) atomicAdd(&stats[t], sh[t]); }
    else      { if (t < 64)  atomicAdd(&stats[t], sh[t]); }
}

// FUSED apply1 + projB: h = elu(bn(c1)) in LDS; s = bn(cs) written IN PLACE into cs;
// PB[n][160] = h@g2 (fp16), R2[n][32] = h@root2+b2. block=192.
__global__ void fuse1_kernel(const float* __restrict__ c1, float* __restrict__ cs,
                             const float* __restrict__ stats, const float* __restrict__ gam1,
                             const float* __restrict__ bet1, const float* __restrict__ gams,
                             const float* __restrict__ bets, const float* __restrict__ g2,
                             const float* __restrict__ root2, const float* __restrict__ b2,
                             __half* __restrict__ PB, float* __restrict__ R2) {
    const int t = threadIdx.x;
    float w[32];
    float b = 0.0f;
    if (t < 160) {
#pragma unroll
        for (int i = 0; i < 32; i++) w[i] = g2[i * 160 + t];
    } else {
        int c = t - 160;
#pragma unroll
        for (int i = 0; i < 32; i++) w[i] = root2[i * 32 + c];
        b = b2[c];
    }
    __shared__ float bscale[32], bshift[32], sscale[32], sshift[32];
    if (t < 32) {
        const float invN = 1.0f / (float)NN;
        float m = stats[t] * invN;
        float v = stats[32 + t] * invN - m * m;
        float sc = gam1[t] * rsqrtf(v + BN_EPS);
        bscale[t] = sc;
        bshift[t] = bet1[t] - m * sc;
        float ms = stats[64 + t] * invN;
        float vs = stats[96 + t] * invN - ms * ms;
        float scs = gams[t] * rsqrtf(vs + BN_EPS);
        sscale[t] = scs;
        sshift[t] = bets[t] - ms * scs;
    }
    __shared__ float xs[8 * 32];
    __syncthreads();
    for (int n0 = blockIdx.x * 8; n0 < NN; n0 += gridDim.x * 8) {
        int rows = NN - n0; if (rows > 8) rows = 8;
        for (int j = t; j < rows * 32; j += 192) {
            int ch = j & 31;
            size_t idx = (size_t)n0 * 32 + j;
            float hv = bscale[ch] * c1[idx] + bshift[ch];
            xs[j] = hv > 0.f ? hv : (__expf(hv) - 1.f);
            cs[idx] = sscale[ch] * cs[idx] + sshift[ch];
        }
        __syncthreads();
        for (int r = 0; r < rows; r++) {
            float acc = b;
#pragma unroll
            for (int i = 0; i < 32; i++) acc += w[i] * xs[r * 32 + i];
            int n = n0 + r;
            if (t < 160) PB[(size_t)n * 160 + t] = __float2half(acc);
            else R2[(size_t)n * 32 + (t - 160)] = acc;
        }
        __syncthreads();
    }
}

// out = elu(bn(c2) + s)
__global__ void apply2_kernel(const float* __restrict__ c2, const float* __restrict__ s_in,
                              const float* __restrict__ stats, const float* __restrict__ gam2,
                              const float* __restrict__ bet2, float* __restrict__ out) {
    int idx = blockIdx.x * blockDim.x + threadIdx.x;
    if (idx >= NN * 32) return;
    int ch = idx & 31;
    const float invN = 1.0f / (float)NN;
    float m = stats[ch] * invN;
    float v = stats[32 + ch] * invN - m * m;
    float o = gam2[ch] * (c2[idx] - m) * rsqrtf(v + BN_EPS) + bet2[ch] + s_in[idx];
    out[idx] = o > 0.f ? o : (__expf(o) - 1.f);
}

extern "C" void kernel_launch(void* const* d_in, const int* in_sizes, int n_in,
                              void* d_out, int out_size, void* d_ws, size_t ws_size,
                              hipStream_t stream) {
    const float* x     = (const float*)d_in[0];
    const float* ea    = (const float*)d_in[1];
    const float* g1    = (const float*)d_in[2];
    const float* mu1   = (const float*)d_in[3];
    const float* sig1  = (const float*)d_in[4];
    const float* root1 = (const float*)d_in[5];
    const float* b1    = (const float*)d_in[6];
    const float* gam1  = (const float*)d_in[7];
    const float* bet1  = (const float*)d_in[8];
    const float* g2    = (const float*)d_in[9];
    const float* mu2   = (const float*)d_in[10];
    const float* sig2  = (const float*)d_in[11];
    const float* root2 = (const float*)d_in[12];
    const float* b2    = (const float*)d_in[13];
    const float* gam2  = (const float*)d_in[14];
    const float* bet2  = (const float*)d_in[15];
    const float* gs    = (const float*)d_in[16];
    const float* mus   = (const float*)d_in[17];
    const float* sigs  = (const float*)d_in[18];
    const float* roots = (const float*)d_in[19];
    const float* bs    = (const float*)d_in[20];
    const float* gams  = (const float*)d_in[21];
    const float* bets  = (const float*)d_in[22];
    const int*   ei    = (const int*)d_in[23];
    float* out = (float*)d_out;

    // ---- workspace layout (fallback uses only the prefix; NEW path adds recsS+M) ----
    char* w = (char*)d_ws;
    __half* PA   = (__half*)w;      w += (size_t)NN * 192 * 2;   // 19.2 MB (reused as PB)
    float*  R1   = (float*)w;       w += (size_t)NN * 32 * 4;    // (reused as R2)
    float*  Rs   = (float*)w;       w += (size_t)NN * 32 * 4;
    float*  c1   = (float*)w;       w += (size_t)NN * 32 * 4;    // (reused as c2)
    float*  cs   = (float*)w;       w += (size_t)NN * 32 * 4;    // s written in place
    int4*   recsA = (int4*)w;       w += (size_t)NE * 16;        // 12.8 MB
    int4*   recsB = (int4*)w;       w += (size_t)NE * 16;        // 12.8 MB
    int*    deg2 = (int*)w;         w += (size_t)NN2 * 4;
    float*  stats = (float*)w;      w += 256 * 4;                // [0..127]=A, [128..191]=B
    int*    rs2  = (int*)w;         w += (size_t)(NN2 + 2) * 4;
    int*    cursor2 = (int*)w;      w += (size_t)NN2 * 4;
    int*    bsum = (int*)w;         w += 512 * 4;
    float*  inv  = (float*)w;       w += 64 * 4;
    int2*   recsS = (int2*)w;       w += (size_t)NE * 8;         // 6.4 MB (NEW only)
    __half* M    = (__half*)w;      w += (size_t)NE * 64;        // 51.2 MB (NEW only)
    const size_t NEED_NEW = (size_t)(w - (char*)d_ws);
    const bool useNew = ws_size >= NEED_NEW;

    const int edgeBlocks  = (NE + 255) / 256;
    const int applyBlocks = (NN * 32 + 255) / 256;

    // deg2 and stats contiguous -> one memset
    hipMemsetAsync(deg2, 0, (size_t)NN2 * 4 + 256 * 4, stream);

    // ---- dual CSR/CSC build ----
    hist_kernel<<<edgeBlocks, 256, 0, stream>>>(ei, deg2, sig1, sig2, sigs, inv);
    block_reduce_kernel<<<NB2, 256, 0, stream>>>(deg2, bsum);
    scan_partials_kernel<<<1, 512, 0, stream>>>(bsum);
    block_scan_kernel<<<NB2, 256, 0, stream>>>(deg2, bsum, rs2, cursor2);

    if (useNew) {
        reorder_new_kernel<<<edgeBlocks, 256, 0, stream>>>(ei, ea, mu1, mu2, mus, inv,
                                                           cursor2, recsA, recsB, recsS);
        projA_kernel<<<512, 256, 0, stream>>>(x, g1, gs, root1, b1, roots, bs, PA, R1, Rs);
        // pass A: conv1 messages (CSC) -> stream-aggregate + 1-line skip gather
        msg_kernel<<<1600, 256, 0, stream>>>(recsA, rs2, PA, 192, M);
        aggA_kernel<<<1600, 256, 0, stream>>>(M, recsS, rs2, PA, R1, Rs, c1, cs, stats);
        fuse1_kernel<<<512, 192, 0, stream>>>(c1, cs, stats, gam1, bet1, gams, bets,
                                              g2, root2, b2, PA, R1);  // PA/R1 reused
        // pass B
        msg_kernel<<<1600, 256, 0, stream>>>(recsB, rs2, PA, 160, M);
        aggB_kernel<<<1600, 256, 0, stream>>>(M, rs2, R1, c1, stats + 128);
        apply2_kernel<<<applyBlocks, 256, 0, stream>>>(c1, cs, stats + 128, gam2, bet2, out);
    } else {
        // proven R6 path
        reorder_fb_kernel<<<edgeBlocks, 256, 0, stream>>>(ei, ea, mu1, mu2, mus, inv,
                                                          cursor2, recsA, recsB);
        projA_kernel<<<512, 256, 0, stream>>>(x, g1, gs, root1, b1, roots, bs, PA, R1, Rs);
        agg_fb_kernel<true><<<2048, 256, 0, stream>>>(recsA, rs2, (const __half2*)PA, 96,
                                                      R1, Rs, c1, cs, stats);
        fuse1_kernel<<<512, 192, 0, stream>>>(c1, cs, stats, gam1, bet1, gams, bets,
                                              g2, root2, b2, PA, R1);
        agg_fb_kernel<false><<<2048, 256, 0, stream>>>(recsB, rs2, (const __half2*)PA, 80,
                                                       R1, nullptr, c1, nullptr, stats + 128);
        apply2_kernel<<<applyBlocks, 256, 0, stream>>>(c1, cs, stats + 128, gam2, bet2, out);
    }
}

// Round 8
// 545.002 us; speedup vs baseline: 1.1627x; 1.1627x over previous
//
#include <hip/hip_runtime.h>
#include <hip/hip_fp16.h>
#include <math.h>

#define NN 50000
#define NE 800000
#define NN2 100000               // concatenated degD||degS
#define GEPS 1e-15f
#define BN_EPS 1e-5f
#define NB2 391                  // ceil((NN2+1)/256)
#define GA_BLKS 512              // conv-stream blocks inside aggA

__device__ __forceinline__ float2 h2f(int bits) {
    __half2 h = *(__half2*)&bits;
    return __half22float2(h);
}
__device__ __forceinline__ int f2h2(float a, float b) {
    __half2 h = __floats2half2_rn(a, b);
    return *(int*)&h;
}

// dual histogram (deg2[0..NN)=dst, deg2[NN..2NN)=src) + (block 0) inv precompute
__global__ void hist_kernel(const int* __restrict__ ei, int* __restrict__ deg2,
                            const float* __restrict__ sig1, const float* __restrict__ sig2,
                            const float* __restrict__ sigs, float* __restrict__ inv) {
    if (blockIdx.x == 0) {
        int t = threadIdx.x;
        if (t < 15)      { float s = sig1[t];      inv[t] = -0.5f / (GEPS + s * s); }
        else if (t < 30) { float s = sig2[t - 15]; inv[t] = -0.5f / (GEPS + s * s); }
        else if (t < 33) { float s = sigs[t - 30]; inv[t] = -0.5f / (GEPS + s * s); }
    }
    int e = blockIdx.x * blockDim.x + threadIdx.x;
    if (e < NE) {
        atomicAdd(&deg2[ei[NE + e]], 1);       // dst
        atomicAdd(&deg2[NN + ei[e]], 1);       // src
    }
}

// ---- two-level scan over deg2[NN2] -> rs2[NN2+1], cursor2[NN2] ----
__global__ void block_reduce_kernel(const int* __restrict__ deg2, int* __restrict__ bsum) {
    __shared__ int sh[256];
    int t = threadIdx.x;
    int i = blockIdx.x * 256 + t;
    sh[t] = (i < NN2) ? deg2[i] : 0;
    __syncthreads();
    for (int off = 128; off > 0; off >>= 1) {
        if (t < off) sh[t] += sh[t + off];
        __syncthreads();
    }
    if (t == 0) bsum[blockIdx.x] = sh[0];
}

__global__ void scan_partials_kernel(int* __restrict__ bsum) {
    __shared__ int sh[512];
    int t = threadIdx.x;
    int v = (t < NB2) ? bsum[t] : 0;
    sh[t] = v;
    __syncthreads();
    for (int off = 1; off < 512; off <<= 1) {
        int u = (t >= off) ? sh[t - off] : 0;
        __syncthreads();
        sh[t] += u;
        __syncthreads();
    }
    if (t < NB2) bsum[t] = sh[t] - v;  // exclusive
}

__global__ void block_scan_kernel(const int* __restrict__ deg2, const int* __restrict__ bsum,
                                  int* __restrict__ rs2, int* __restrict__ cursor2) {
    __shared__ int sh[256];
    int t = threadIdx.x;
    int i = blockIdx.x * 256 + t;
    int v = (i < NN2) ? deg2[i] : 0;
    sh[t] = v;
    __syncthreads();
    for (int off = 1; off < 256; off <<= 1) {
        int u = (t >= off) ? sh[t - off] : 0;
        __syncthreads();
        sh[t] += u;
        __syncthreads();
    }
    int excl = sh[t] - v + bsum[blockIdx.x];
    if (i <= NN2) rs2[i] = excl;
    if (i < NN2) cursor2[i] = excl;
}

// ---- NEW path reorder: CSC-ordered weight recs carrying the CSR slot ----
// recsA[poss] = {posd, (w1_0,w1_1),(w1_2,w1_3),(w1_4,0)}   (CSC order)
// recsB[poss] = {posd, (w2_0,w2_1),(w2_2,w2_3),(w2_4,0)}   (CSC order)
// recsS[posd] = {src, (ws,0)}                              (CSR order)
__global__ void reorder_new_kernel(const int* __restrict__ ei, const float* __restrict__ ea,
                                   const float* __restrict__ mu1, const float* __restrict__ mu2,
                                   const float* __restrict__ mus, const float* __restrict__ inv,
                                   int* __restrict__ cursor2, int4* __restrict__ recsA,
                                   int4* __restrict__ recsB, int2* __restrict__ recsS) {
    int e = blockIdx.x * blockDim.x + threadIdx.x;
    if (e >= NE) return;
    int src = ei[e];
    int dst = ei[NE + e];
    float a0 = ea[e * 3 + 0], a1 = ea[e * 3 + 1], a2 = ea[e * 3 + 2];

    float w1[5], w2[5], ws;
#pragma unroll
    for (int k = 0; k < 5; k++) {
        float d0 = a0 - mu1[k * 3 + 0], d1 = a1 - mu1[k * 3 + 1], d2 = a2 - mu1[k * 3 + 2];
        w1[k] = __expf(inv[k * 3] * d0 * d0 + inv[k * 3 + 1] * d1 * d1 + inv[k * 3 + 2] * d2 * d2);
    }
#pragma unroll
    for (int k = 0; k < 5; k++) {
        float d0 = a0 - mu2[k * 3 + 0], d1 = a1 - mu2[k * 3 + 1], d2 = a2 - mu2[k * 3 + 2];
        w2[k] = __expf(inv[15 + k * 3] * d0 * d0 + inv[15 + k * 3 + 1] * d1 * d1 +
                       inv[15 + k * 3 + 2] * d2 * d2);
    }
    {
        float d0 = a0 - mus[0], d1 = a1 - mus[1], d2 = a2 - mus[2];
        ws = __expf(inv[30] * d0 * d0 + inv[31] * d1 * d1 + inv[32] * d2 * d2);
    }
    int posd = atomicAdd(&cursor2[dst], 1);
    int poss = atomicAdd(&cursor2[NN + src], 1) - NE;
    int4 ra, rb;
    ra.x = posd; ra.y = f2h2(w1[0], w1[1]); ra.z = f2h2(w1[2], w1[3]); ra.w = f2h2(w1[4], 0.f);
    rb.x = posd; rb.y = f2h2(w2[0], w2[1]); rb.z = f2h2(w2[2], w2[3]); rb.w = f2h2(w2[4], 0.f);
    recsA[poss] = ra;
    recsB[poss] = rb;
    int2 rs; rs.x = src; rs.y = f2h2(ws, 0.f);
    recsS[posd] = rs;
}

// ---- FALLBACK reorder (R6 format): CSR-ordered {src, weights} ----
__global__ void reorder_fb_kernel(const int* __restrict__ ei, const float* __restrict__ ea,
                                  const float* __restrict__ mu1, const float* __restrict__ mu2,
                                  const float* __restrict__ mus, const float* __restrict__ inv,
                                  int* __restrict__ cursor2, int4* __restrict__ recsA,
                                  int4* __restrict__ recsB) {
    int e = blockIdx.x * blockDim.x + threadIdx.x;
    if (e >= NE) return;
    int src = ei[e];
    int dst = ei[NE + e];
    float a0 = ea[e * 3 + 0], a1 = ea[e * 3 + 1], a2 = ea[e * 3 + 2];

    float w1[5], w2[5], ws;
#pragma unroll
    for (int k = 0; k < 5; k++) {
        float d0 = a0 - mu1[k * 3 + 0], d1 = a1 - mu1[k * 3 + 1], d2 = a2 - mu1[k * 3 + 2];
        w1[k] = __expf(inv[k * 3] * d0 * d0 + inv[k * 3 + 1] * d1 * d1 + inv[k * 3 + 2] * d2 * d2);
    }
#pragma unroll
    for (int k = 0; k < 5; k++) {
        float d0 = a0 - mu2[k * 3 + 0], d1 = a1 - mu2[k * 3 + 1], d2 = a2 - mu2[k * 3 + 2];
        w2[k] = __expf(inv[15 + k * 3] * d0 * d0 + inv[15 + k * 3 + 1] * d1 * d1 +
                       inv[15 + k * 3 + 2] * d2 * d2);
    }
    {
        float d0 = a0 - mus[0], d1 = a1 - mus[1], d2 = a2 - mus[2];
        ws = __expf(inv[30] * d0 * d0 + inv[31] * d1 * d1 + inv[32] * d2 * d2);
    }
    int pos = atomicAdd(&cursor2[dst], 1);
    int4 ra, rb;
    ra.x = src; ra.y = f2h2(w1[0], w1[1]); ra.z = f2h2(w1[2], w1[3]); ra.w = f2h2(w1[4], ws);
    rb.x = src; rb.y = f2h2(w2[0], w2[1]); rb.z = f2h2(w2[2], w2[3]); rb.w = f2h2(w2[4], 0.f);
    recsA[pos] = ra;
    recsB[pos] = rb;
}

// pass A projection: x -> PA[n][192] fp16 (0..159: g1-proj, 160..191: gs-proj),
//                    R1[n][32] fp32 (x@root1+b1), Rs[n][32] fp32 (x@roots+bs). block=256.
__global__ void projA_kernel(const float* __restrict__ x, const float* __restrict__ g1,
                             const float* __restrict__ gs, const float* __restrict__ root1,
                             const float* __restrict__ b1, const float* __restrict__ roots,
                             const float* __restrict__ bs, __half* __restrict__ PA,
                             float* __restrict__ R1, float* __restrict__ Rs) {
    const int t = threadIdx.x;
    float w[32];
    float b = 0.0f;
    if (t < 160) {
#pragma unroll
        for (int i = 0; i < 32; i++) w[i] = g1[i * 160 + t];
    } else if (t < 192) {
        int c = t - 160;
#pragma unroll
        for (int i = 0; i < 32; i++) w[i] = gs[i * 32 + c];
    } else if (t < 224) {
        int c = t - 192;
#pragma unroll
        for (int i = 0; i < 32; i++) w[i] = root1[i * 32 + c];
        b = b1[c];
    } else {
        int c = t - 224;
#pragma unroll
        for (int i = 0; i < 32; i++) w[i] = roots[i * 32 + c];
        b = bs[c];
    }
    __shared__ float xs[8 * 32];
    for (int n0 = blockIdx.x * 8; n0 < NN; n0 += gridDim.x * 8) {
        int rows = NN - n0; if (rows > 8) rows = 8;
        for (int j = t; j < rows * 32; j += 256) xs[j] = x[(size_t)n0 * 32 + j];
        __syncthreads();
        for (int r = 0; r < rows; r++) {
            float acc = b;
#pragma unroll
            for (int i = 0; i < 32; i++) acc += w[i] * xs[r * 32 + i];
            int n = n0 + r;
            if (t < 192) PA[(size_t)n * 192 + t] = __float2half(acc);
            else if (t < 224) R1[(size_t)n * 32 + (t - 192)] = acc;
            else Rs[(size_t)n * 32 + (t - 224)] = acc;
        }
        __syncthreads();
    }
}

// ---- message kernel (CSC). Wave per src; row in registers; half-wave per edge,
// 2 edges in flight, 2-deep rec prefetch; one coalesced 64B store per edge. ----
__global__ void msg_kernel(const int4* __restrict__ recs, const int* __restrict__ rs2,
                           const __half* __restrict__ T, int strideH, __half* __restrict__ M) {
    const int tid = blockIdx.x * blockDim.x + threadIdx.x;
    const int lane = threadIdx.x & 63;
    const int ch = lane & 31;
    const int half = lane >> 5;
    const int wavesTotal = (gridDim.x * blockDim.x) >> 6;
    const int wid = tid >> 6;
    for (int s = wid; s < NN; s += wavesTotal) {
        const int start = rs2[NN + s] - NE;
        const int end   = rs2[NN + s + 1] - NE;
        if (start >= end) continue;
        const __half* row = T + (size_t)s * strideH;
        float v0 = __half2float(row[ch]);
        float v1 = __half2float(row[32 + ch]);
        float v2 = __half2float(row[64 + ch]);
        float v3 = __half2float(row[96 + ch]);
        float v4 = __half2float(row[128 + ch]);
        int pos = start + half;
        if (pos < end) {
            int4 q = recs[pos];
            while (true) {
                int nxt = pos + 2;
                bool has = nxt < end;
                int4 qn;
                if (has) qn = recs[nxt];
                float2 u0 = h2f(q.y), u1 = h2f(q.z), u2 = h2f(q.w);
                float m = u0.x * v0 + u0.y * v1 + u1.x * v2 + u1.y * v3 + u2.x * v4;
                M[(size_t)q.x * 32 + ch] = __float2half(m);
                if (!has) break;
                pos = nxt; q = qn;
            }
        }
    }
}

// ---- wide streaming reduce of contiguous M segments. Lane loads int4 (8 halves);
// wave covers 16 rows/iter. chb=(8*lane)%32 is loop-invariant -> butterfly reduce. ----
__device__ __forceinline__ void stream_reduce_role(
        const __half* __restrict__ M, const int* __restrict__ rs2,
        const float* __restrict__ R, float* __restrict__ c,
        float* __restrict__ statsDst, float* sh, int wid, int wavesTotal, int lane) {
    const int chb = (lane * 8) & 31;
    float sreg[8], qreg[8];
#pragma unroll
    for (int j = 0; j < 8; j++) { sreg[j] = 0.f; qreg[j] = 0.f; }
    for (int n = wid; n < NN; n += wavesTotal) {
        const int start = rs2[n], end = rs2[n + 1];
        const int endE = end * 32;
        float acc[8];
#pragma unroll
        for (int j = 0; j < 8; j++) acc[j] = 0.f;
        int eb = start * 32 + lane * 8;
        for (; eb + 8 <= endE; eb += 512) {
            int4 q = *(const int4*)(M + eb);
            float2 a;
            a = h2f(q.x); acc[0] += a.x; acc[1] += a.y;
            a = h2f(q.y); acc[2] += a.x; acc[3] += a.y;
            a = h2f(q.z); acc[4] += a.x; acc[5] += a.y;
            a = h2f(q.w); acc[6] += a.x; acc[7] += a.y;
        }
        if (eb < endE) {
            int rem = endE - eb;
#pragma unroll
            for (int j = 0; j < 8; j++)
                if (j < rem) acc[j] += __half2float(M[eb + j]);
        }
#pragma unroll
        for (int j = 0; j < 8; j++) {
            acc[j] += __shfl_xor(acc[j], 4, 64);
            acc[j] += __shfl_xor(acc[j], 8, 64);
            acc[j] += __shfl_xor(acc[j], 16, 64);
            acc[j] += __shfl_xor(acc[j], 32, 64);
        }
        if (lane < 4) {
            const float invd = 1.0f / fmaxf((float)(end - start), 1.0f);
#pragma unroll
            for (int j = 0; j < 8; j++) {
                float v = acc[j] * invd + R[(size_t)n * 32 + chb + j];
                c[(size_t)n * 32 + chb + j] = v;
                sreg[j] += v;
                qreg[j] += v * v;
            }
        }
    }
    if (lane < 4) {
#pragma unroll
        for (int j = 0; j < 8; j++) {
            atomicAdd(&sh[chb + j], sreg[j]);
            atomicAdd(&sh[32 + chb + j], qreg[j]);
        }
    }
    __syncthreads();
    if (threadIdx.x < 64) atomicAdd(&statsDst[threadIdx.x], sh[threadIdx.x]);
}

// aggA: blocks < GA_BLKS stream-reduce conv M; remaining blocks do the 1-line/edge
// skip gather (4 groups x 16 lanes). stats: conv->base 0, skip->base 64.
__global__ void aggA_kernel(const __half* __restrict__ M, const int2* __restrict__ recsS,
                            const int* __restrict__ rs2, const __half* __restrict__ PA,
                            const float* __restrict__ R, const float* __restrict__ Rs,
                            float* __restrict__ c, float* __restrict__ cs,
                            float* __restrict__ stats) {
    __shared__ float sh[64];
    if (threadIdx.x < 64) sh[threadIdx.x] = 0.f;
    __syncthreads();
    const int lane = threadIdx.x & 63;
    if (blockIdx.x < GA_BLKS) {
        int wid = (int)((blockIdx.x * blockDim.x + threadIdx.x) >> 6);
        int wavesTotal = (GA_BLKS * blockDim.x) >> 6;
        stream_reduce_role(M, rs2, R, c, stats, sh, wid, wavesTotal, lane);
    } else {
        int bid = blockIdx.x - GA_BLKS;
        int wid = (int)((bid * blockDim.x + threadIdx.x) >> 6);
        int wavesTotal = ((gridDim.x - GA_BLKS) * blockDim.x) >> 6;
        const int grp = lane >> 4, ch2 = lane & 15;
        float sx = 0.f, sy = 0.f, qx = 0.f, qy = 0.f;
        for (int n = wid; n < NN; n += wavesTotal) {
            int start = rs2[n], end = rs2[n + 1];
            float ax = 0.f, ay = 0.f;
            for (int pos = start + grp; pos < end; pos += 4) {
                int2 sr = recsS[pos];
                float ws = h2f(sr.y).x;
                __half2 pv = *(const __half2*)(PA + (size_t)sr.x * 192 + 160 + 2 * ch2);
                float2 p = __half22float2(pv);
                ax += ws * p.x;
                ay += ws * p.y;
            }
            ax += __shfl_xor(ax, 16, 64); ax += __shfl_xor(ax, 32, 64);
            ay += __shfl_xor(ay, 16, 64); ay += __shfl_xor(ay, 32, 64);
            if (grp == 0) {
                float invd = 1.f / fmaxf((float)(end - start), 1.f);
                float2 rv = ((const float2*)(Rs + (size_t)n * 32))[ch2];
                float vx = ax * invd + rv.x;
                float vy = ay * invd + rv.y;
                ((float2*)(cs + (size_t)n * 32))[ch2] = make_float2(vx, vy);
                sx += vx; sy += vy; qx += vx * vx; qy += vy * vy;
            }
        }
        if (grp == 0) {
            atomicAdd(&sh[2 * ch2], sx);      atomicAdd(&sh[2 * ch2 + 1], sy);
            atomicAdd(&sh[32 + 2 * ch2], qx); atomicAdd(&sh[32 + 2 * ch2 + 1], qy);
        }
        __syncthreads();
        if (threadIdx.x < 64) atomicAdd(&stats[64 + threadIdx.x], sh[threadIdx.x]);
    }
}

// aggB: pure wide streaming reduce -> c2, stats base passed in.
__global__ void aggB_kernel(const __half* __restrict__ M, const int* __restrict__ rs2,
                            const float* __restrict__ R, float* __restrict__ c,
                            float* __restrict__ stats) {
    __shared__ float sh[64];
    if (threadIdx.x < 64) sh[threadIdx.x] = 0.f;
    __syncthreads();
    const int lane = threadIdx.x & 63;
    int wid = (int)((blockIdx.x * blockDim.x + threadIdx.x) >> 6);
    int wavesTotal = (gridDim.x * blockDim.x) >> 6;
    stream_reduce_role(M, rs2, R, c, stats, sh, wid, wavesTotal, lane);
}

// ---- FALLBACK agg (R6, proven): CSR gather, 16B recs ----
template <bool SKIP>
__global__ void agg_fb_kernel(const int4* __restrict__ recs, const int* __restrict__ rowstart,
                              const __half2* __restrict__ P, int strideH2,
                              const float* __restrict__ R, const float* __restrict__ Rs,
                              float* __restrict__ c, float* __restrict__ cs,
                              float* __restrict__ stats) {
    const int tid = blockIdx.x * blockDim.x + threadIdx.x;
    const int lane = threadIdx.x & 63;
    const int grp = lane >> 4;
    const int ch2 = lane & 15;
    const int wavesTotal = (gridDim.x * blockDim.x) >> 6;
    const int wid = tid >> 6;

    float s1x = 0.f, s1y = 0.f, q1x = 0.f, q1y = 0.f;
    float ssx = 0.f, ssy = 0.f, qsx = 0.f, qsy = 0.f;

    for (int n = wid; n < NN; n += wavesTotal) {
        const int start = rowstart[n];
        const int end = rowstart[n + 1];
        const int d = end - start;
        float m1x = 0.f, m1y = 0.f, mSx = 0.f, mSy = 0.f;
        for (int i = start + grp; i < end; i += 4) {
            const int4 q = recs[i];
            const __half2* prow = P + (size_t)q.x * strideH2 + ch2;
            float2 p0 = __half22float2(prow[0]);
            float2 p1 = __half22float2(prow[16]);
            float2 p2 = __half22float2(prow[32]);
            float2 p3 = __half22float2(prow[48]);
            float2 p4 = __half22float2(prow[64]);
            float2 u0 = h2f(q.y), u1 = h2f(q.z), u2 = h2f(q.w);
            m1x += u0.x * p0.x + u0.y * p1.x + u1.x * p2.x + u1.y * p3.x + u2.x * p4.x;
            m1y += u0.x * p0.y + u0.y * p1.y + u1.x * p2.y + u1.y * p3.y + u2.x * p4.y;
            if (SKIP) {
                float2 ps = __half22float2(prow[80]);
                mSx += u2.y * ps.x;
                mSy += u2.y * ps.y;
            }
        }
        m1x += __shfl_xor(m1x, 16, 64); m1x += __shfl_xor(m1x, 32, 64);
        m1y += __shfl_xor(m1y, 16, 64); m1y += __shfl_xor(m1y, 32, 64);
        if (SKIP) {
            mSx += __shfl_xor(mSx, 16, 64); mSx += __shfl_xor(mSx, 32, 64);
            mSy += __shfl_xor(mSy, 16, 64); mSy += __shfl_xor(mSy, 32, 64);
        }
        const float invd = 1.0f / fmaxf((float)d, 1.0f);
        if (grp == 0) {
            float2 rv = ((const float2*)(R + (size_t)n * 32))[ch2];
            float vx = m1x * invd + rv.x;
            float vy = m1y * invd + rv.y;
            ((float2*)(c + (size_t)n * 32))[ch2] = make_float2(vx, vy);
            s1x += vx; s1y += vy; q1x += vx * vx; q1y += vy * vy;
            if (SKIP) {
                float2 rs = ((const float2*)(Rs + (size_t)n * 32))[ch2];
                float wx = mSx * invd + rs.x;
                float wy = mSy * invd + rs.y;
                ((float2*)(cs + (size_t)n * 32))[ch2] = make_float2(wx, wy);
                ssx += wx; ssy += wy; qsx += wx * wx; qsy += wy * wy;
            }
        }
    }
    __shared__ float sh[128];
    const int t = threadIdx.x;
    if (t < 128) sh[t] = 0.f;
    __syncthreads();
    if (grp == 0) {
        atomicAdd(&sh[2 * ch2], s1x);       atomicAdd(&sh[2 * ch2 + 1], s1y);
        atomicAdd(&sh[32 + 2 * ch2], q1x);  atomicAdd(&sh[32 + 2 * ch2 + 1], q1y);
        if (SKIP) {
            atomicAdd(&sh[64 + 2 * ch2], ssx);  atomicAdd(&sh[64 + 2 * ch2 + 1], ssy);
            atomicAdd(&sh[96 + 2 * ch2], qsx);  atomicAdd(&sh[96 + 2 * ch2 + 1], qsy);
        }
    }
    __syncthreads();
    if (SKIP) { if (t < 128) atomicAdd(&stats[t], sh[t]); }
    else      { if (t < 64)  atomicAdd(&stats[t], sh[t]); }
}

// FUSED apply1 + projB: h = elu(bn(c1)) in LDS; s = bn(cs) written IN PLACE into cs;
// PB[n][160] = h@g2 (fp16), R2[n][32] = h@root2+b2. block=192.
__global__ void fuse1_kernel(const float* __restrict__ c1, float* __restrict__ cs,
                             const float* __restrict__ stats, const float* __restrict__ gam1,
                             const float* __restrict__ bet1, const float* __restrict__ gams,
                             const float* __restrict__ bets, const float* __restrict__ g2,
                             const float* __restrict__ root2, const float* __restrict__ b2,
                             __half* __restrict__ PB, float* __restrict__ R2) {
    const int t = threadIdx.x;
    float w[32];
    float b = 0.0f;
    if (t < 160) {
#pragma unroll
        for (int i = 0; i < 32; i++) w[i] = g2[i * 160 + t];
    } else {
        int c = t - 160;
#pragma unroll
        for (int i = 0; i < 32; i++) w[i] = root2[i * 32 + c];
        b = b2[c];
    }
    __shared__ float bscale[32], bshift[32], sscale[32], sshift[32];
    if (t < 32) {
        const float invN = 1.0f / (float)NN;
        float m = stats[t] * invN;
        float v = stats[32 + t] * invN - m * m;
        float sc = gam1[t] * rsqrtf(v + BN_EPS);
        bscale[t] = sc;
        bshift[t] = bet1[t] - m * sc;
        float ms = stats[64 + t] * invN;
        float vs = stats[96 + t] * invN - ms * ms;
        float scs = gams[t] * rsqrtf(vs + BN_EPS);
        sscale[t] = scs;
        sshift[t] = bets[t] - ms * scs;
    }
    __shared__ float xs[8 * 32];
    __syncthreads();
    for (int n0 = blockIdx.x * 8; n0 < NN; n0 += gridDim.x * 8) {
        int rows = NN - n0; if (rows > 8) rows = 8;
        for (int j = t; j < rows * 32; j += 192) {
            int ch = j & 31;
            size_t idx = (size_t)n0 * 32 + j;
            float hv = bscale[ch] * c1[idx] + bshift[ch];
            xs[j] = hv > 0.f ? hv : (__expf(hv) - 1.f);
            cs[idx] = sscale[ch] * cs[idx] + sshift[ch];
        }
        __syncthreads();
        for (int r = 0; r < rows; r++) {
            float acc = b;
#pragma unroll
            for (int i = 0; i < 32; i++) acc += w[i] * xs[r * 32 + i];
            int n = n0 + r;
            if (t < 160) PB[(size_t)n * 160 + t] = __float2half(acc);
            else R2[(size_t)n * 32 + (t - 160)] = acc;
        }
        __syncthreads();
    }
}

// out = elu(bn(c2) + s)
__global__ void apply2_kernel(const float* __restrict__ c2, const float* __restrict__ s_in,
                              const float* __restrict__ stats, const float* __restrict__ gam2,
                              const float* __restrict__ bet2, float* __restrict__ out) {
    int idx = blockIdx.x * blockDim.x + threadIdx.x;
    if (idx >= NN * 32) return;
    int ch = idx & 31;
    const float invN = 1.0f / (float)NN;
    float m = stats[ch] * invN;
    float v = stats[32 + ch] * invN - m * m;
    float o = gam2[ch] * (c2[idx] - m) * rsqrtf(v + BN_EPS) + bet2[ch] + s_in[idx];
    out[idx] = o > 0.f ? o : (__expf(o) - 1.f);
}

extern "C" void kernel_launch(void* const* d_in, const int* in_sizes, int n_in,
                              void* d_out, int out_size, void* d_ws, size_t ws_size,
                              hipStream_t stream) {
    const float* x     = (const float*)d_in[0];
    const float* ea    = (const float*)d_in[1];
    const float* g1    = (const float*)d_in[2];
    const float* mu1   = (const float*)d_in[3];
    const float* sig1  = (const float*)d_in[4];
    const float* root1 = (const float*)d_in[5];
    const float* b1    = (const float*)d_in[6];
    const float* gam1  = (const float*)d_in[7];
    const float* bet1  = (const float*)d_in[8];
    const float* g2    = (const float*)d_in[9];
    const float* mu2   = (const float*)d_in[10];
    const float* sig2  = (const float*)d_in[11];
    const float* root2 = (const float*)d_in[12];
    const float* b2    = (const float*)d_in[13];
    const float* gam2  = (const float*)d_in[14];
    const float* bet2  = (const float*)d_in[15];
    const float* gs    = (const float*)d_in[16];
    const float* mus   = (const float*)d_in[17];
    const float* sigs  = (const float*)d_in[18];
    const float* roots = (const float*)d_in[19];
    const float* bs    = (const float*)d_in[20];
    const float* gams  = (const float*)d_in[21];
    const float* bets  = (const float*)d_in[22];
    const int*   ei    = (const int*)d_in[23];
    float* out = (float*)d_out;

    // ---- workspace layout (16B-padded bump allocator) ----
    char* base = (char*)d_ws;
    size_t off = 0;
    auto alloc = [&](size_t bytes) -> char* {
        char* p = base + off;
        off += (bytes + 15) & ~(size_t)15;
        return p;
    };
    __half* PA    = (__half*)alloc((size_t)NN * 192 * 2);   // 19.2 MB (reused as PB)
    float*  R1    = (float*)alloc((size_t)NN * 32 * 4);     // (reused as R2)
    float*  Rs    = (float*)alloc((size_t)NN * 32 * 4);
    float*  c1    = (float*)alloc((size_t)NN * 32 * 4);     // (reused as c2)
    float*  cs    = (float*)alloc((size_t)NN * 32 * 4);     // s written in place
    int4*   recsA = (int4*)alloc((size_t)NE * 16);          // 12.8 MB
    int4*   recsB = (int4*)alloc((size_t)NE * 16);          // 12.8 MB

    // decide NEW vs fallback: NEW additionally needs M (51.2 MB) + recsS (6.4 MB)
    const size_t commonOff = off;
    const size_t intsBytes = (size_t)NN2 * 4 + 16 + 768 + 16 + ((size_t)(NN2 + 4) * 4) +
                             (size_t)NN2 * 4 + 16 + 1568 + 16 + 144 + 16;
    const size_t needNew = commonOff + (size_t)NE * 64 + (size_t)NE * 8 + intsBytes + 256;
    const bool useNew = ws_size >= needNew;

    __half* M = nullptr;
    int2* recsS = nullptr;
    if (useNew) {
        M     = (__half*)alloc((size_t)NE * 32 * 2);        // 51.2 MB
        recsS = (int2*)alloc((size_t)NE * 8);               // 6.4 MB
    }
    int*   deg2    = (int*)alloc((size_t)NN2 * 4);
    float* stats   = (float*)alloc(768);                    // [0..63]=conv1,[64..127]=skip,[128..191]=conv2
    int*   rs2     = (int*)alloc((size_t)(NN2 + 4) * 4);
    int*   cursor2 = (int*)alloc((size_t)NN2 * 4);
    int*   bsum    = (int*)alloc(1568);
    float* inv     = (float*)alloc(144);

    const int edgeBlocks  = (NE + 255) / 256;
    const int applyBlocks = (NN * 32 + 255) / 256;

    // deg2 and stats contiguous -> one memset covers both
    hipMemsetAsync(deg2, 0, (size_t)NN2 * 4 + 768, stream);

    // ---- dual CSR/CSC build ----
    hist_kernel<<<edgeBlocks, 256, 0, stream>>>(ei, deg2, sig1, sig2, sigs, inv);
    block_reduce_kernel<<<NB2, 256, 0, stream>>>(deg2, bsum);
    scan_partials_kernel<<<1, 512, 0, stream>>>(bsum);
    block_scan_kernel<<<NB2, 256, 0, stream>>>(deg2, bsum, rs2, cursor2);

    if (useNew) {
        reorder_new_kernel<<<edgeBlocks, 256, 0, stream>>>(ei, ea, mu1, mu2, mus, inv,
                                                           cursor2, recsA, recsB, recsS);
        projA_kernel<<<512, 256, 0, stream>>>(x, g1, gs, root1, b1, roots, bs, PA, R1, Rs);
        // pass A: conv1 messages (CSC) -> combined stream-reduce + skip gather
        msg_kernel<<<1600, 256, 0, stream>>>(recsA, rs2, PA, 192, M);
        aggA_kernel<<<2048, 256, 0, stream>>>(M, recsS, rs2, PA, R1, Rs, c1, cs, stats);
        fuse1_kernel<<<512, 192, 0, stream>>>(c1, cs, stats, gam1, bet1, gams, bets,
                                              g2, root2, b2, PA, R1);  // PA/R1 reused
        // pass B
        msg_kernel<<<1600, 256, 0, stream>>>(recsB, rs2, PA, 160, M);
        aggB_kernel<<<1024, 256, 0, stream>>>(M, rs2, R1, c1, stats + 128);
        apply2_kernel<<<applyBlocks, 256, 0, stream>>>(c1, cs, stats + 128, gam2, bet2, out);
    } else {
        // proven R6 path
        reorder_fb_kernel<<<edgeBlocks, 256, 0, stream>>>(ei, ea, mu1, mu2, mus, inv,
                                                          cursor2, recsA, recsB);
        projA_kernel<<<512, 256, 0, stream>>>(x, g1, gs, root1, b1, roots, bs, PA, R1, Rs);
        agg_fb_kernel<true><<<2048, 256, 0, stream>>>(recsA, rs2, (const __half2*)PA, 96,
                                                      R1, Rs, c1, cs, stats);
        fuse1_kernel<<<512, 192, 0, stream>>>(c1, cs, stats, gam1, bet1, gams, bets,
                                              g2, root2, b2, PA, R1);
        agg_fb_kernel<false><<<2048, 256, 0, stream>>>(recsB, rs2, (const __half2*)PA, 80,
                                                       R1, nullptr, c1, nullptr, stats + 128);
        apply2_kernel<<<applyBlocks, 256, 0, stream>>>(c1, cs, stats + 128, gam2, bet2, out);
    }
}